// Round 13
// baseline (56.955 us; speedup 1.0000x reference)
//
#include <hip/hip_runtime.h>
#include <hip/hip_bf16.h>

#define NB 2
#define NN 768
#define NC 64
#define NPH 32
#define NAH 32
#define NEGV -1e9f
#define LOG2E 1.4426950408889634f

typedef __attribute__((ext_vector_type(8))) short bf16x8;
typedef __attribute__((ext_vector_type(4))) float f32x4;
typedef __attribute__((ext_vector_type(2))) float f32x2;

__device__ __forceinline__ short f2bf(float f) {
    unsigned u = __builtin_bit_cast(unsigned, f);
    u = (u + 0x7FFFu + ((u >> 16) & 1u)) >> 16;
    return (short)u;
}

// packed 2xbf16 convert (RNE), 1 instruction for 2 values
__device__ __forceinline__ unsigned cvt_pk_bf16(float lo, float hi) {
    unsigned r;
    asm("v_cvt_pk_bf16_f32 %0, %1, %2" : "=v"(r) : "v"(lo), "v"(hi));
    return r;
}

__device__ __forceinline__ float bflo(unsigned u) { return __builtin_bit_cast(float, u << 16); }
__device__ __forceinline__ float bfhi(unsigned u) { return __builtin_bit_cast(float, u & 0xffff0000u); }

// async DMA: global (per-lane addr) -> LDS (wave-uniform base + lane*16). Zero VGPR cost.
__device__ __forceinline__ void gload_lds16(const void* g, void* l) {
    __builtin_amdgcn_global_load_lds(
        (const __attribute__((address_space(1))) unsigned int*)g,
        (__attribute__((address_space(3))) unsigned int*)l,
        16, 0, 0);
}

// ---------------- Kernel 1: x = MLP(coords); lane-packed bf16 vtσ(+pm_b2); qc; kW1(f32);
//                  hc = coords@pm_w1; packed mask bits; transposed bf16 weight tables ----------------
__global__ __launch_bounds__(64)
void embed_kernel(const float* __restrict__ coords,
                  const float* __restrict__ ce_w1, const float* __restrict__ ce_b1,
                  const float* __restrict__ ce_w2, const float* __restrict__ ce_b2,
                  const float* __restrict__ wq, const float* __restrict__ wk,
                  const float* __restrict__ wv,
                  const float* __restrict__ am_w1, const float* __restrict__ am_b1,
                  const float* __restrict__ pm_w1,
                  const float* __restrict__ pm_w2, const float* __restrict__ pm_b2,
                  const float* __restrict__ am_w2,
                  const void* __restrict__ maskp,
                  float* __restrict__ x, short* __restrict__ vth,
                  float* __restrict__ qc, float* __restrict__ kw1,
                  float* __restrict__ hcf,
                  unsigned long long* __restrict__ maskw,
                  short* __restrict__ w12T, short* __restrict__ peT,
                  short* __restrict__ a2P)
{
    const int row = blockIdx.x;   // b*N + n
    const int c = threadIdx.x;    // channel
    __shared__ float h1[NC];
    __shared__ float xs[NC];
    __shared__ float qs[NC];
    __shared__ float ks[NC];
    __shared__ int cnt;
    if (c == 0) cnt = 0;
    float p0 = coords[row*3+0], p1 = coords[row*3+1], p2 = coords[row*3+2];
    // hc = coords @ pm_w1 (no bias; b1 re-added for the i-side in attn)
    if (c < NPH) {
        float hcv = fmaf(p0, pm_w1[c], fmaf(p1, pm_w1[NPH+c], p2 * pm_w1[2*NPH+c]));
        hcf[row*NPH + c] = hcv;
    }
    float h = fmaf(p0, ce_w1[c], fmaf(p1, ce_w1[NC+c], fmaf(p2, ce_w1[2*NC+c], ce_b1[c])));
    h1[c] = fmaxf(h, 0.f);
    __syncthreads();
    float acc = ce_b2[c];
    for (int d = 0; d < NC; ++d) acc = fmaf(h1[d], ce_w2[d*NC+c], acc);
    xs[c] = acc;
    x[row*NC+c] = acc;
    __syncthreads();
    float aq = 0.f, ak = 0.f, av = 0.f;
    for (int d = 0; d < NC; ++d) {
        float xv = xs[d];
        aq = fmaf(xv, wq[d*NC+c], aq);
        ak = fmaf(xv, wk[d*NC+c], ak);
        av = fmaf(xv, wv[d*NC+c], av);
    }
    qs[c] = aq; ks[c] = ak;
    // lane-packed bf16 vtσ: value (j-local jj, channel c) of tile -> [lane = (jj>>2)*16 + (c&15)]
    //   [k = (c>>4)*4 + (jj&3)]; reader lane (kgp,cl) k (nt,r) gets vt[c=nt*16+cl][j=kgp*4+r]
    {
        int bb = row / NN, nn = row - bb*NN;
        int tile = nn >> 4, jj = nn & 15;
        int lp = ((jj >> 2) << 4) | (c & 15);
        int kp = ((c >> 4) << 2) | (jj & 3);
        vth[((size_t)bb*48 + tile)*1024 + lp*16 + kp] = f2bf(av + pm_b2[c]);
    }
    __syncthreads();
    if (c < NAH) {
        // qc = (q + pm_b2) @ am_w1 + am_b1
        float a2 = am_b1[c];
        for (int d = 0; d < NC; ++d) a2 = fmaf(qs[d] + pm_b2[d], am_w1[d*NAH+c], a2);
        qc[row*NAH+c] = a2;
    } else {
        int hh = c - NAH;
        float a2 = 0.f;
        for (int d = 0; d < NC; ++d) a2 = fmaf(ks[d], am_w1[d*NAH+hh], a2);
        kw1[row*NAH+hh] = a2;
    }

    if (row == 0) {
        // mask dtype detection (bool-as-uint8 ~1382 bytes==1; int32 <=384), then bit-pack
        const unsigned char* mB = (const unsigned char*)maskp;
        const int* mI = (const int*)maskp;
        int local = 0;
        for (int t = c; t < NB*NN; t += NC) local += (mB[t] == 1) ? 1 : 0;
        atomicAdd(&cnt, local);
        __syncthreads();
        int isByte = (cnt > 800);
        if (c < 24) {
            unsigned long long bits = 0ull;
            for (int e = 0; e < 64; ++e) {
                int j = c*64 + e;
                int mv = isByte ? (int)mB[j] : mI[j];
                bits |= (unsigned long long)((mv != 0) ? 1 : 0) << e;
            }
            maskw[c] = bits;
        }
    }
    if (row >= 1 && row <= 8) {
        // w12T[c2*32 + p] = W12[p][c2], W12 = pm_w2 @ am_w1 (32x32), bf16
        int ri = row - 1;
        #pragma unroll
        for (int t = 0; t < 2; ++t) {
            int o = ri*128 + c*2 + t;
            int c2 = o >> 5, p = o & 31;
            float a2 = 0.f;
            for (int d = 0; d < NC; ++d) a2 = fmaf(pm_w2[p*NC+d], am_w1[d*NAH+c2], a2);
            w12T[o] = f2bf(a2);
        }
    }
    if (row >= 9 && row <= 16) {
        // peT[cc*32 + h] = pm_w2[h][cc], bf16
        int ri = row - 9;
        #pragma unroll
        for (int t = 0; t < 4; ++t) {
            int o = ri*256 + c*4 + t;
            int cc = o >> 5, hh = o & 31;
            peT[o] = f2bf(pm_w2[hh*NC + cc]);
        }
    }
    if (row >= 17 && row <= 24) {
        // a2P[cc*32 + s] = am_w2[h(s)][cc]*log2e, h(s) = ((s&7)>>2)*16 + (s>>3)*4 + (s&3)
        int ri = row - 17;
        #pragma unroll
        for (int t = 0; t < 4; ++t) {
            int o = ri*256 + c*4 + t;
            int cc = o >> 5, s = o & 31;
            int e = s & 7, kg = s >> 3;
            int hh = ((e >> 2) << 4) + kg*4 + (e & 3);
            a2P[o] = f2bf(am_w2[hh*NC + cc] * LOG2E);
        }
    }
}

// ---------------- Kernel 2: r12 structure (full DMA staging, vmcnt(6), mask in C-init)
//                  + packed-f32 (v_pk_*) elementwise: hp/relu, f8/relu, softmax accum ----------------
// Block = 4 waves, handles i-pair (2*blockIdx.x, +1). Wave w does j-tiles w, w+4, ... (12).
__global__ __launch_bounds__(256, 3)
void attn_kernel(const float* __restrict__ pm_b1,
                 const float* __restrict__ out_w, const float* __restrict__ out_b,
                 const float* __restrict__ xg,
                 const short* __restrict__ vth,
                 const float* __restrict__ qcg, const float* __restrict__ kw1g,
                 const float* __restrict__ hcfg,
                 const unsigned long long* __restrict__ maskw,
                 const short* __restrict__ w12T, const short* __restrict__ peT,
                 const short* __restrict__ a2P,
                 float* __restrict__ out)
{
    const int tid  = threadIdx.x;
    const int wv   = tid >> 6;
    const int lane = tid & 63;
    const int cl   = lane & 15;         // A/B-frag row/col
    const int kgp  = lane >> 4;         // k-group

    const int bi0 = blockIdx.x * 2;     // first of the i-pair (same b: NN even)
    const int b   = bi0 / NN;

    // [wave][buf]: kv0|kv1|vv0|vv1|hj0|hj1, 1KB each = 6KB/buf; 48KB total.
    __shared__ __align__(16) char stage[4][2][6144];
    // comb/agg alias the stage region (dead after the main loop; barrier before reuse)
    float* combp = (float*)&stage[0][0][0];   // [2][2][4][NC] = 1024 floats
    float* aggp  = combp + 1024;              // [2][NC] = 128 floats

    // ---- weight fragments: contiguous b128 loads from transposed tables ----
    bf16x8 bPE[4], bW12[2], bA2[4];
    #pragma unroll
    for (int nt = 0; nt < 4; ++nt) bPE[nt] = *(const bf16x8*)(peT + (nt*16+cl)*NPH + kgp*8);
    #pragma unroll
    for (int ht = 0; ht < 2; ++ht) bW12[ht] = *(const bf16x8*)(w12T + (ht*16+cl)*NPH + kgp*8);
    #pragma unroll
    for (int nt = 0; nt < 4; ++nt) bA2[nt] = *(const bf16x8*)(a2P + (nt*16+cl)*NPH + kgp*8);

    // ---- per-i state: qc C-init and hc_i + b1 ----
    f32x4 qcC[2][2], hciA[2][2];
    {
        f32x4 b1a = *(const f32x4*)(pm_b1 + kgp*8);
        f32x4 b1b = *(const f32x4*)(pm_b1 + kgp*8 + 4);
        #pragma unroll
        for (int g = 0; g < 2; ++g) {
            #pragma unroll
            for (int ht = 0; ht < 2; ++ht)
                qcC[g][ht] = *(const f32x4*)(qcg + (size_t)(bi0+g)*NAH + ht*16 + kgp*4);
            f32x4 h0 = *(const f32x4*)(hcfg + (size_t)(bi0+g)*NPH + kgp*8);
            f32x4 h1 = *(const f32x4*)(hcfg + (size_t)(bi0+g)*NPH + kgp*8 + 4);
            hciA[g][0] = h0 + b1a;
            hciA[g][1] = h1 + b1b;
        }
    }

    const int maskBase = b * NN;
    const float* krow = kw1g + (size_t)(maskBase + wv*16 + cl) * NAH + kgp*4;
    const short* vvp  = vth + ((size_t)b*48 + wv)*1024 + (size_t)lane*16;
    const float* hjr  = hcfg + (size_t)(maskBase + wv*16 + cl) * NPH + kgp*8;
    const unsigned long long* mwp = maskw + b*12;
    const int shft = wv*16 + kgp*4;

    // packed accumulators: l2/ac2 hold {partial(r0,r1), partial(r2,r3)} halves
    f32x2 l2_[2][4], ac2_[2][4];
    #pragma unroll
    for (int g = 0; g < 2; ++g)
        #pragma unroll
        for (int nt = 0; nt < 4; ++nt) {
            l2_[g][nt] = (f32x2){0.f, 0.f};
            ac2_[g][nt] = (f32x2){0.f, 0.f};
        }
    const f32x4 z4 = {0.f, 0.f, 0.f, 0.f};

    // issue tile t's 6 DMA loads into buf (per-lane global src, linear lane*16 LDS dst)
    auto stage_tile = [&](int t, int buf) {
        char* base = &stage[wv][buf][0];
        const float* kr = krow + (size_t)t*2048;   // 64 rows * NAH floats / tile-group
        const short* vs = vvp  + (size_t)t*4096;   // 4*1024 shorts
        const float* hr = hjr  + (size_t)t*2048;   // 64 rows * NPH floats
        gload_lds16(kr,      base);
        gload_lds16(kr + 16, base + 1024);
        gload_lds16(vs,      base + 2048);
        gload_lds16(vs + 8,  base + 3072);
        gload_lds16(hr,      base + 4096);
        gload_lds16(hr + 4,  base + 5120);
    };

    stage_tile(0, 0);

    for (int p = 0; p < 12; ++p) {
        // prefetch next tile, then wait only for tile p (next's 6 stay in flight)
        if (p < 11) {
            stage_tile(p + 1, (p + 1) & 1);
            asm volatile("s_waitcnt vmcnt(6)" ::: "memory");
        } else {
            asm volatile("s_waitcnt vmcnt(0)" ::: "memory");
        }

        // read back this wave's private slots (stride-1 lane*16: conflict-free)
        const char* base = &stage[wv][p & 1][0];
        f32x4 kv0  = *(const f32x4*)(base + (size_t)lane*16);
        f32x4 kv1  = *(const f32x4*)(base + 1024 + (size_t)lane*16);
        bf16x8 vv0 = *(const bf16x8*)(base + 2048 + (size_t)lane*16);
        bf16x8 vv1 = *(const bf16x8*)(base + 3072 + (size_t)lane*16);
        f32x4 hj0  = *(const f32x4*)(base + 4096 + (size_t)lane*16);
        f32x4 hj1  = *(const f32x4*)(base + 5120 + (size_t)lane*16);
        unsigned bits4 = (unsigned)(mwp[p] >> shft) & 0xFu;

        // mask as logits C-init: C row r (= j = kgp*4+r) masked -> -1e9; exp2 -> exact 0
        f32x4 maskC;
        #pragma unroll
        for (int r = 0; r < 4; ++r) maskC[r] = (bits4 & (1u << r)) ? 0.f : NEGV;

        // unpack vtσ -> f32 C-init (v_j + pm_b2)
        const unsigned* vq0 = (const unsigned*)&vv0;
        const unsigned* vq1 = (const unsigned*)&vv1;
        f32x4 vA[4];
        vA[0][0]=bflo(vq0[0]); vA[0][1]=bfhi(vq0[0]); vA[0][2]=bflo(vq0[1]); vA[0][3]=bfhi(vq0[1]);
        vA[1][0]=bflo(vq0[2]); vA[1][1]=bfhi(vq0[2]); vA[1][2]=bflo(vq0[3]); vA[1][3]=bfhi(vq0[3]);
        vA[2][0]=bflo(vq1[0]); vA[2][1]=bfhi(vq1[0]); vA[2][2]=bflo(vq1[1]); vA[2][3]=bfhi(vq1[1]);
        vA[3][0]=bflo(vq1[2]); vA[3][1]=bfhi(vq1[2]); vA[3][2]=bflo(vq1[3]); vA[3][3]=bfhi(vq1[3]);

        // ---- two independent i-chains over the shared tile ----
        #pragma unroll
        for (int g = 0; g < 2; ++g) {
            // hp = relu(hc_i + b1 - hc_j)  [packed f32: v_pk_add(neg) + v_pk_max]
            f32x4 hv01 = __builtin_elementwise_max(hciA[g][0] - hj0, z4);
            f32x4 hv23 = __builtin_elementwise_max(hciA[g][1] - hj1, z4);
            union { bf16x8 h8; unsigned u[4]; } aHP;
            aHP.u[0] = cvt_pk_bf16(hv01[0], hv01[1]);
            aHP.u[1] = cvt_pk_bf16(hv01[2], hv01[3]);
            aHP.u[2] = cvt_pk_bf16(hv23[0], hv23[1]);
            aHP.u[3] = cvt_pk_bf16(hv23[2], hv23[3]);

            // PE + v_j (C-init = vtσ)
            f32x4 pe[4];
            #pragma unroll
            for (int nt = 0; nt < 4; ++nt)
                pe[nt] = __builtin_amdgcn_mfma_f32_16x16x32_bf16(aHP.h8, bPE[nt], vA[nt], 0, 0, 0);

            // H^T = W12^T @ hp^T + qc
            f32x4 hT[2];
            #pragma unroll
            for (int ht = 0; ht < 2; ++ht)
                hT[ht] = __builtin_amdgcn_mfma_f32_16x16x32_bf16(bW12[ht], aHP.h8, qcC[g][ht], 0, 0, 0);

            // relu(H^T - kW1)  [packed], repack as logits A-frag (slot e = ht*4+r)
            f32x4 f80 = __builtin_elementwise_max(hT[0] - kv0, z4);
            f32x4 f81 = __builtin_elementwise_max(hT[1] - kv1, z4);
            union { bf16x8 h8; unsigned u[4]; } aH;
            aH.u[0] = cvt_pk_bf16(f80[0], f80[1]);
            aH.u[1] = cvt_pk_bf16(f80[2], f80[3]);
            aH.u[2] = cvt_pk_bf16(f81[0], f81[1]);
            aH.u[3] = cvt_pk_bf16(f81[2], f81[3]);

            // logits (log2-domain, mask pre-added via C-init) + packed exp2 accumulation
            #pragma unroll
            for (int nt = 0; nt < 4; ++nt) {
                f32x4 atl = __builtin_amdgcn_mfma_f32_16x16x32_bf16(aH.h8, bA2[nt], maskC, 0, 0, 0);
                f32x4 pp4;
                pp4[0] = __builtin_amdgcn_exp2f(atl[0]);
                pp4[1] = __builtin_amdgcn_exp2f(atl[1]);
                pp4[2] = __builtin_amdgcn_exp2f(atl[2]);
                pp4[3] = __builtin_amdgcn_exp2f(atl[3]);
                f32x2 plo = __builtin_shufflevector(pp4, pp4, 0, 1);
                f32x2 phi = __builtin_shufflevector(pp4, pp4, 2, 3);
                f32x2 pelo = __builtin_shufflevector(pe[nt], pe[nt], 0, 1);
                f32x2 pehi = __builtin_shufflevector(pe[nt], pe[nt], 2, 3);
                // {partial01, partial23} halves: 2 pk_add + 2 pk_fma replace 4 add + 4 fma
                f32x2 lacc = l2_[g][nt];
                lacc = lacc + plo;
                lacc = lacc + phi;
                l2_[g][nt] = lacc;
                f32x2 aacc = ac2_[g][nt];
                aacc = __builtin_elementwise_fma(plo, pelo, aacc);
                aacc = __builtin_elementwise_fma(phi, pehi, aacc);
                ac2_[g][nt] = aacc;
            }
        }
    }

    // collapse packed halves, then combine the 4 row-group streams (plain sums)
    float l_[2][4], ac_[2][4];
    #pragma unroll
    for (int g = 0; g < 2; ++g)
        #pragma unroll
        for (int nt = 0; nt < 4; ++nt) {
            l_[g][nt]  = l2_[g][nt][0] + l2_[g][nt][1];
            ac_[g][nt] = ac2_[g][nt][0] + ac2_[g][nt][1];
        }
    #pragma unroll
    for (int st = 16; st <= 32; st <<= 1) {
        #pragma unroll
        for (int g = 0; g < 2; ++g)
            #pragma unroll
            for (int nt = 0; nt < 4; ++nt) {
                l_[g][nt]  += __shfl_xor(l_[g][nt], st);
                ac_[g][nt] += __shfl_xor(ac_[g][nt], st);
            }
    }

    __syncthreads();   // all waves done with stage -> safe to reuse as comb/agg

    if (lane < 16) {
        #pragma unroll
        for (int g = 0; g < 2; ++g)
            #pragma unroll
            for (int nt = 0; nt < 4; ++nt) {
                combp[((0*2+g)*4 + wv)*NC + nt*16+lane] = l_[g][nt];
                combp[((1*2+g)*4 + wv)*NC + nt*16+lane] = ac_[g][nt];
            }
    }
    __syncthreads();

    if (tid < 128) {
        int g = tid >> 6, c = tid & 63;
        float lt = 0.f, at2 = 0.f;
        #pragma unroll
        for (int w = 0; w < 4; ++w) {
            lt  += combp[((0*2+g)*4 + w)*NC + c];
            at2 += combp[((1*2+g)*4 + w)*NC + c];
        }
        aggp[g*NC + c] = at2 / lt;
    }
    __syncthreads();

    if (tid < 128) {
        int g = tid >> 6, c = tid & 63;
        int bi2 = bi0 + g;
        float o = out_b[c] + xg[(size_t)bi2*NC + c];
        for (int d = 0; d < NC; ++d) o = fmaf(aggp[g*NC + d], out_w[d*NC + c], o);
        out[(size_t)bi2*NC + c] = o;
    }
}

extern "C" void kernel_launch(void* const* d_in, const int* in_sizes, int n_in,
                              void* d_out, int out_size, void* d_ws, size_t ws_size,
                              hipStream_t stream) {
    const float* coords = (const float*)d_in[0];
    const void*  maskp  = d_in[1];
    const float* ce_w1  = (const float*)d_in[2];
    const float* ce_b1  = (const float*)d_in[3];
    const float* ce_w2  = (const float*)d_in[4];
    const float* ce_b2  = (const float*)d_in[5];
    const float* wq     = (const float*)d_in[6];
    const float* wk     = (const float*)d_in[7];
    const float* wvw    = (const float*)d_in[8];
    const float* pm_w1  = (const float*)d_in[9];
    const float* pm_b1  = (const float*)d_in[10];
    const float* pm_w2  = (const float*)d_in[11];
    const float* pm_b2  = (const float*)d_in[12];
    const float* am_w1  = (const float*)d_in[13];
    const float* am_b1  = (const float*)d_in[14];
    const float* am_w2  = (const float*)d_in[15];
    // d_in[16] = am_b2: cancels in per-channel softmax, unused
    const float* out_w  = (const float*)d_in[17];
    const float* out_b  = (const float*)d_in[18];

    char* ws = (char*)d_ws;
    unsigned long long* maskw = (unsigned long long*)ws;      // 24 * 8 B
    short* w12T = (short*)(ws + 256);                         // 2 KB
    short* peT  = (short*)(ws + 4096);                        // 4 KB
    short* a2P  = (short*)(ws + 8192);                        // 4 KB
    // r5-identical slot layout (vtσ bf16 lives in the old 384K vt slot)
    float* x    = (float*)(ws + 16384);                       // 384 KB
    short* vth  = (short*)(x + (size_t)NB*NN*NC);             // 192 KB used of 384 KB slot
    float* qc   = x + 2*(size_t)NB*NN*NC;                     // 192 KB
    float* kw1  = qc + (size_t)NB*NN*NAH;                     // 192 KB
    float* hcf  = kw1 + (size_t)NB*NN*NAH;                    // 192 KB

    embed_kernel<<<NB*NN, 64, 0, stream>>>(coords, ce_w1, ce_b1, ce_w2, ce_b2,
                                           wq, wk, wvw, am_w1, am_b1, pm_w1, pm_w2, pm_b2, am_w2,
                                           maskp, x, vth, qc, kw1, hcf, maskw, w12T, peT, a2P);
    attn_kernel<<<NB*NN/2, 256, 0, stream>>>(pm_b1, out_w, out_b,
                                             x, vth, qc, kw1, hcf,
                                             maskw, w12T, peT, a2P,
                                             (float*)d_out);
}

// Round 14
// 49.434 us; speedup vs baseline: 1.1521x; 1.1521x over previous
//
#include <hip/hip_runtime.h>
#include <hip/hip_bf16.h>

#define NB 2
#define NN 768
#define NC 64
#define NPH 32
#define NAH 32
#define NEGV -1e9f
#define LOG2E 1.4426950408889634f

typedef __attribute__((ext_vector_type(8))) short bf16x8;
typedef __attribute__((ext_vector_type(4))) float f32x4;

__device__ __forceinline__ short f2bf(float f) {
    unsigned u = __builtin_bit_cast(unsigned, f);
    u = (u + 0x7FFFu + ((u >> 16) & 1u)) >> 16;
    return (short)u;
}

// packed 2xbf16 convert (RNE), 1 instruction for 2 values
__device__ __forceinline__ unsigned cvt_pk_bf16(float lo, float hi) {
    unsigned r;
    asm("v_cvt_pk_bf16_f32 %0, %1, %2" : "=v"(r) : "v"(lo), "v"(hi));
    return r;
}

__device__ __forceinline__ float bflo(unsigned u) { return __builtin_bit_cast(float, u << 16); }
__device__ __forceinline__ float bfhi(unsigned u) { return __builtin_bit_cast(float, u & 0xffff0000u); }

// async DMA: global (per-lane addr) -> LDS (wave-uniform base + lane*16). Zero VGPR cost.
__device__ __forceinline__ void gload_lds16(const void* g, void* l) {
    __builtin_amdgcn_global_load_lds(
        (const __attribute__((address_space(1))) unsigned int*)g,
        (__attribute__((address_space(3))) unsigned int*)l,
        16, 0, 0);
}

// ---------------- Kernel 1: x = MLP(coords); lane-packed bf16 vtσ(+pm_b2); qc; kW1(f32);
//                  hc = coords@pm_w1; packed mask bits; transposed bf16 weight tables ----------------
__global__ __launch_bounds__(64)
void embed_kernel(const float* __restrict__ coords,
                  const float* __restrict__ ce_w1, const float* __restrict__ ce_b1,
                  const float* __restrict__ ce_w2, const float* __restrict__ ce_b2,
                  const float* __restrict__ wq, const float* __restrict__ wk,
                  const float* __restrict__ wv,
                  const float* __restrict__ am_w1, const float* __restrict__ am_b1,
                  const float* __restrict__ pm_w1,
                  const float* __restrict__ pm_w2, const float* __restrict__ pm_b2,
                  const float* __restrict__ am_w2,
                  const void* __restrict__ maskp,
                  float* __restrict__ x, short* __restrict__ vth,
                  float* __restrict__ qc, float* __restrict__ kw1,
                  float* __restrict__ hcf,
                  unsigned long long* __restrict__ maskw,
                  short* __restrict__ w12T, short* __restrict__ peT,
                  short* __restrict__ a2P)
{
    const int row = blockIdx.x;   // b*N + n
    const int c = threadIdx.x;    // channel
    __shared__ float h1[NC];
    __shared__ float xs[NC];
    __shared__ float qs[NC];
    __shared__ float ks[NC];
    __shared__ int cnt;
    if (c == 0) cnt = 0;
    float p0 = coords[row*3+0], p1 = coords[row*3+1], p2 = coords[row*3+2];
    // hc = coords @ pm_w1 (no bias; b1 re-added for the i-side in attn)
    if (c < NPH) {
        float hcv = fmaf(p0, pm_w1[c], fmaf(p1, pm_w1[NPH+c], p2 * pm_w1[2*NPH+c]));
        hcf[row*NPH + c] = hcv;
    }
    float h = fmaf(p0, ce_w1[c], fmaf(p1, ce_w1[NC+c], fmaf(p2, ce_w1[2*NC+c], ce_b1[c])));
    h1[c] = fmaxf(h, 0.f);
    __syncthreads();
    float acc = ce_b2[c];
    for (int d = 0; d < NC; ++d) acc = fmaf(h1[d], ce_w2[d*NC+c], acc);
    xs[c] = acc;
    x[row*NC+c] = acc;
    __syncthreads();
    float aq = 0.f, ak = 0.f, av = 0.f;
    for (int d = 0; d < NC; ++d) {
        float xv = xs[d];
        aq = fmaf(xv, wq[d*NC+c], aq);
        ak = fmaf(xv, wk[d*NC+c], ak);
        av = fmaf(xv, wv[d*NC+c], av);
    }
    qs[c] = aq; ks[c] = ak;
    // lane-packed bf16 vtσ: value (j-local jj, channel c) of tile -> [lane = (jj>>2)*16 + (c&15)]
    //   [k = (c>>4)*4 + (jj&3)]; reader lane (kgp,cl) k (nt,r) gets vt[c=nt*16+cl][j=kgp*4+r]
    {
        int bb = row / NN, nn = row - bb*NN;
        int tile = nn >> 4, jj = nn & 15;
        int lp = ((jj >> 2) << 4) | (c & 15);
        int kp = ((c >> 4) << 2) | (jj & 3);
        vth[((size_t)bb*48 + tile)*1024 + lp*16 + kp] = f2bf(av + pm_b2[c]);
    }
    __syncthreads();
    // qc = (q + pm_b2) @ am_w1 + am_b1 (lanes 0-31); kw1 = k @ am_w1 (lanes 32-63)
    // uniform loop (no exec-mask split: one 64-iter pass instead of two serial ones)
    {
        int cc = c & 31;
        bool isQ = (c < NAH);
        float a2 = isQ ? am_b1[cc] : 0.f;
        for (int d = 0; d < NC; ++d) {
            float src = isQ ? (qs[d] + pm_b2[d]) : ks[d];
            a2 = fmaf(src, am_w1[d*NAH+cc], a2);
        }
        if (isQ) qc[row*NAH+cc] = a2;
        else     kw1[row*NAH+cc] = a2;
    }

    if (row == 0) {
        // mask dtype detection (bool-as-uint8 ~1382 bytes==1; int32 <=384), then bit-pack
        const unsigned char* mB = (const unsigned char*)maskp;
        const int* mI = (const int*)maskp;
        int local = 0;
        for (int t = c; t < NB*NN; t += NC) local += (mB[t] == 1) ? 1 : 0;
        atomicAdd(&cnt, local);
        __syncthreads();
        int isByte = (cnt > 800);
        if (c < 24) {
            unsigned long long bits = 0ull;
            for (int e = 0; e < 64; ++e) {
                int j = c*64 + e;
                int mv = isByte ? (int)mB[j] : mI[j];
                bits |= (unsigned long long)((mv != 0) ? 1 : 0) << e;
            }
            maskw[c] = bits;
        }
    }
    if (row >= 1 && row <= 8) {
        // w12T[c2*32 + p] = W12[p][c2], W12 = pm_w2 @ am_w1 (32x32), bf16
        int ri = row - 1;
        #pragma unroll
        for (int t = 0; t < 2; ++t) {
            int o = ri*128 + c*2 + t;
            int c2 = o >> 5, p = o & 31;
            float a2 = 0.f;
            for (int d = 0; d < NC; ++d) a2 = fmaf(pm_w2[p*NC+d], am_w1[d*NAH+c2], a2);
            w12T[o] = f2bf(a2);
        }
    }
    if (row >= 9 && row <= 16) {
        // peT[cc*32 + h] = pm_w2[h][cc], bf16
        int ri = row - 9;
        #pragma unroll
        for (int t = 0; t < 4; ++t) {
            int o = ri*256 + c*4 + t;
            int cc = o >> 5, hh = o & 31;
            peT[o] = f2bf(pm_w2[hh*NC + cc]);
        }
    }
    if (row >= 17 && row <= 24) {
        // a2P[cc*32 + s] = am_w2[h(s)][cc]*log2e, h(s) = ((s&7)>>2)*16 + (s>>3)*4 + (s&3)
        int ri = row - 17;
        #pragma unroll
        for (int t = 0; t < 4; ++t) {
            int o = ri*256 + c*4 + t;
            int cc = o >> 5, s = o & 31;
            int e = s & 7, kg = s >> 3;
            int hh = ((e >> 2) << 4) + kg*4 + (e & 3);
            a2P[o] = f2bf(am_w2[hh*NC + cc] * LOG2E);
        }
    }
}

// ---------------- Kernel 2: r12 structure (reverted from r13): full DMA staging via
//                  global_load_lds double-buffer, exact vmcnt(6), mask in logits C-init ----------------
// Block = 4 waves, handles i-pair (2*blockIdx.x, +1). Wave w does j-tiles w, w+4, ... (12).
__global__ __launch_bounds__(256, 3)
void attn_kernel(const float* __restrict__ pm_b1,
                 const float* __restrict__ out_w, const float* __restrict__ out_b,
                 const float* __restrict__ xg,
                 const short* __restrict__ vth,
                 const float* __restrict__ qcg, const float* __restrict__ kw1g,
                 const float* __restrict__ hcfg,
                 const unsigned long long* __restrict__ maskw,
                 const short* __restrict__ w12T, const short* __restrict__ peT,
                 const short* __restrict__ a2P,
                 float* __restrict__ out)
{
    const int tid  = threadIdx.x;
    const int wv   = tid >> 6;
    const int lane = tid & 63;
    const int cl   = lane & 15;         // A/B-frag row/col
    const int kgp  = lane >> 4;         // k-group

    const int bi0 = blockIdx.x * 2;     // first of the i-pair (same b: NN even)
    const int b   = bi0 / NN;

    // [wave][buf]: kv0|kv1|vv0|vv1|hj0|hj1, 1KB each = 6KB/buf; 48KB total.
    __shared__ __align__(16) char stage[4][2][6144];
    // comb/agg alias the stage region (dead after the main loop; barrier before reuse)
    float* combp = (float*)&stage[0][0][0];   // [2][2][4][NC] = 1024 floats
    float* aggp  = combp + 1024;              // [2][NC] = 128 floats

    // ---- weight fragments: contiguous b128 loads from transposed tables ----
    bf16x8 bPE[4], bW12[2], bA2[4];
    #pragma unroll
    for (int nt = 0; nt < 4; ++nt) bPE[nt] = *(const bf16x8*)(peT + (nt*16+cl)*NPH + kgp*8);
    #pragma unroll
    for (int ht = 0; ht < 2; ++ht) bW12[ht] = *(const bf16x8*)(w12T + (ht*16+cl)*NPH + kgp*8);
    #pragma unroll
    for (int nt = 0; nt < 4; ++nt) bA2[nt] = *(const bf16x8*)(a2P + (nt*16+cl)*NPH + kgp*8);

    // ---- per-i state: qc C-init and hc_i + b1 ----
    f32x4 qcC[2][2], hciA[2][2];
    {
        f32x4 b1a = *(const f32x4*)(pm_b1 + kgp*8);
        f32x4 b1b = *(const f32x4*)(pm_b1 + kgp*8 + 4);
        #pragma unroll
        for (int g = 0; g < 2; ++g) {
            #pragma unroll
            for (int ht = 0; ht < 2; ++ht)
                qcC[g][ht] = *(const f32x4*)(qcg + (size_t)(bi0+g)*NAH + ht*16 + kgp*4);
            f32x4 h0 = *(const f32x4*)(hcfg + (size_t)(bi0+g)*NPH + kgp*8);
            f32x4 h1 = *(const f32x4*)(hcfg + (size_t)(bi0+g)*NPH + kgp*8 + 4);
            hciA[g][0] = h0 + b1a;
            hciA[g][1] = h1 + b1b;
        }
    }

    const int maskBase = b * NN;
    const float* krow = kw1g + (size_t)(maskBase + wv*16 + cl) * NAH + kgp*4;
    const short* vvp  = vth + ((size_t)b*48 + wv)*1024 + (size_t)lane*16;
    const float* hjr  = hcfg + (size_t)(maskBase + wv*16 + cl) * NPH + kgp*8;
    const unsigned long long* mwp = maskw + b*12;
    const int shft = wv*16 + kgp*4;

    float l_[2][4], ac_[2][4];
    #pragma unroll
    for (int g = 0; g < 2; ++g)
        #pragma unroll
        for (int nt = 0; nt < 4; ++nt) { l_[g][nt] = 0.f; ac_[g][nt] = 0.f; }

    // issue tile t's 6 DMA loads into buf (per-lane global src, linear lane*16 LDS dst)
    auto stage_tile = [&](int t, int buf) {
        char* base = &stage[wv][buf][0];
        const float* kr = krow + (size_t)t*2048;   // 64 rows * NAH floats / tile-group
        const short* vs = vvp  + (size_t)t*4096;   // 4*1024 shorts
        const float* hr = hjr  + (size_t)t*2048;   // 64 rows * NPH floats
        gload_lds16(kr,      base);
        gload_lds16(kr + 16, base + 1024);
        gload_lds16(vs,      base + 2048);
        gload_lds16(vs + 8,  base + 3072);
        gload_lds16(hr,      base + 4096);
        gload_lds16(hr + 4,  base + 5120);
    };

    stage_tile(0, 0);

    for (int p = 0; p < 12; ++p) {
        // prefetch next tile, then wait only for tile p (next's 6 stay in flight)
        if (p < 11) {
            stage_tile(p + 1, (p + 1) & 1);
            asm volatile("s_waitcnt vmcnt(6)" ::: "memory");
        } else {
            asm volatile("s_waitcnt vmcnt(0)" ::: "memory");
        }

        // read back this wave's private slots (stride-1 lane*16: conflict-free)
        const char* base = &stage[wv][p & 1][0];
        f32x4 kv0  = *(const f32x4*)(base + (size_t)lane*16);
        f32x4 kv1  = *(const f32x4*)(base + 1024 + (size_t)lane*16);
        bf16x8 vv0 = *(const bf16x8*)(base + 2048 + (size_t)lane*16);
        bf16x8 vv1 = *(const bf16x8*)(base + 3072 + (size_t)lane*16);
        f32x4 hj0  = *(const f32x4*)(base + 4096 + (size_t)lane*16);
        f32x4 hj1  = *(const f32x4*)(base + 5120 + (size_t)lane*16);
        unsigned bits4 = (unsigned)(mwp[p] >> shft) & 0xFu;

        // mask as logits C-init: C row r (= j = kgp*4+r) masked -> -1e9; exp2 -> exact 0
        f32x4 maskC;
        #pragma unroll
        for (int r = 0; r < 4; ++r) maskC[r] = (bits4 & (1u << r)) ? 0.f : NEGV;

        // unpack vtσ -> f32 C-init (v_j + pm_b2)
        const unsigned* vq0 = (const unsigned*)&vv0;
        const unsigned* vq1 = (const unsigned*)&vv1;
        f32x4 vA[4];
        vA[0][0]=bflo(vq0[0]); vA[0][1]=bfhi(vq0[0]); vA[0][2]=bflo(vq0[1]); vA[0][3]=bfhi(vq0[1]);
        vA[1][0]=bflo(vq0[2]); vA[1][1]=bfhi(vq0[2]); vA[1][2]=bflo(vq0[3]); vA[1][3]=bfhi(vq0[3]);
        vA[2][0]=bflo(vq1[0]); vA[2][1]=bfhi(vq1[0]); vA[2][2]=bflo(vq1[1]); vA[2][3]=bfhi(vq1[1]);
        vA[3][0]=bflo(vq1[2]); vA[3][1]=bfhi(vq1[2]); vA[3][2]=bflo(vq1[3]); vA[3][3]=bfhi(vq1[3]);

        // ---- two independent i-chains over the shared tile ----
        #pragma unroll
        for (int g = 0; g < 2; ++g) {
            // hp = relu(hc_i + b1 - hc_j)
            float hv[8];
            #pragma unroll
            for (int e = 0; e < 4; ++e) {
                hv[e]   = fmaxf(hciA[g][0][e] - hj0[e], 0.f);
                hv[4+e] = fmaxf(hciA[g][1][e] - hj1[e], 0.f);
            }
            union { bf16x8 h8; unsigned u[4]; } aHP;
            #pragma unroll
            for (int p2 = 0; p2 < 4; ++p2) aHP.u[p2] = cvt_pk_bf16(hv[2*p2], hv[2*p2+1]);

            // PE + v_j (C-init = vtσ)
            f32x4 pe[4];
            #pragma unroll
            for (int nt = 0; nt < 4; ++nt)
                pe[nt] = __builtin_amdgcn_mfma_f32_16x16x32_bf16(aHP.h8, bPE[nt], vA[nt], 0, 0, 0);

            // H^T = W12^T @ hp^T + qc
            f32x4 hT[2];
            #pragma unroll
            for (int ht = 0; ht < 2; ++ht)
                hT[ht] = __builtin_amdgcn_mfma_f32_16x16x32_bf16(bW12[ht], aHP.h8, qcC[g][ht], 0, 0, 0);

            // relu(H^T - kW1), repack as logits A-frag (slot e = ht*4+r)
            float f8[8];
            #pragma unroll
            for (int r = 0; r < 4; ++r) {
                f8[r]   = fmaxf(hT[0][r] - kv0[r], 0.f);
                f8[4+r] = fmaxf(hT[1][r] - kv1[r], 0.f);
            }
            union { bf16x8 h8; unsigned u[4]; } aH;
            #pragma unroll
            for (int p2 = 0; p2 < 4; ++p2) aH.u[p2] = cvt_pk_bf16(f8[2*p2], f8[2*p2+1]);

            // logits (log2-domain, mask pre-added via C-init) + maxless exp2 accumulation
            #pragma unroll
            for (int nt = 0; nt < 4; ++nt) {
                f32x4 atl = __builtin_amdgcn_mfma_f32_16x16x32_bf16(aH.h8, bA2[nt], maskC, 0, 0, 0);
                #pragma unroll
                for (int r = 0; r < 4; ++r) {
                    float pp = __builtin_amdgcn_exp2f(atl[r]);
                    l_[g][nt] += pp;
                    ac_[g][nt] = fmaf(pp, pe[nt][r], ac_[g][nt]);
                }
            }
        }
    }

    // combine the 4 row-group streams within the wave (plain sums)
    #pragma unroll
    for (int st = 16; st <= 32; st <<= 1) {
        #pragma unroll
        for (int g = 0; g < 2; ++g)
            #pragma unroll
            for (int nt = 0; nt < 4; ++nt) {
                l_[g][nt]  += __shfl_xor(l_[g][nt], st);
                ac_[g][nt] += __shfl_xor(ac_[g][nt], st);
            }
    }

    __syncthreads();   // all waves done with stage -> safe to reuse as comb/agg

    if (lane < 16) {
        #pragma unroll
        for (int g = 0; g < 2; ++g)
            #pragma unroll
            for (int nt = 0; nt < 4; ++nt) {
                combp[((0*2+g)*4 + wv)*NC + nt*16+lane] = l_[g][nt];
                combp[((1*2+g)*4 + wv)*NC + nt*16+lane] = ac_[g][nt];
            }
    }
    __syncthreads();

    if (tid < 128) {
        int g = tid >> 6, c = tid & 63;
        float lt = 0.f, at2 = 0.f;
        #pragma unroll
        for (int w = 0; w < 4; ++w) {
            lt  += combp[((0*2+g)*4 + w)*NC + c];
            at2 += combp[((1*2+g)*4 + w)*NC + c];
        }
        aggp[g*NC + c] = at2 / lt;
    }
    __syncthreads();

    if (tid < 128) {
        int g = tid >> 6, c = tid & 63;
        int bi2 = bi0 + g;
        float o = out_b[c] + xg[(size_t)bi2*NC + c];
        for (int d = 0; d < NC; ++d) o = fmaf(aggp[g*NC + d], out_w[d*NC + c], o);
        out[(size_t)bi2*NC + c] = o;
    }
}

extern "C" void kernel_launch(void* const* d_in, const int* in_sizes, int n_in,
                              void* d_out, int out_size, void* d_ws, size_t ws_size,
                              hipStream_t stream) {
    const float* coords = (const float*)d_in[0];
    const void*  maskp  = d_in[1];
    const float* ce_w1  = (const float*)d_in[2];
    const float* ce_b1  = (const float*)d_in[3];
    const float* ce_w2  = (const float*)d_in[4];
    const float* ce_b2  = (const float*)d_in[5];
    const float* wq     = (const float*)d_in[6];
    const float* wk     = (const float*)d_in[7];
    const float* wvw    = (const float*)d_in[8];
    const float* pm_w1  = (const float*)d_in[9];
    const float* pm_b1  = (const float*)d_in[10];
    const float* pm_w2  = (const float*)d_in[11];
    const float* pm_b2  = (const float*)d_in[12];
    const float* am_w1  = (const float*)d_in[13];
    const float* am_b1  = (const float*)d_in[14];
    const float* am_w2  = (const float*)d_in[15];
    // d_in[16] = am_b2: cancels in per-channel softmax, unused
    const float* out_w  = (const float*)d_in[17];
    const float* out_b  = (const float*)d_in[18];

    char* ws = (char*)d_ws;
    unsigned long long* maskw = (unsigned long long*)ws;      // 24 * 8 B
    short* w12T = (short*)(ws + 256);                         // 2 KB
    short* peT  = (short*)(ws + 4096);                        // 4 KB
    short* a2P  = (short*)(ws + 8192);                        // 4 KB
    // r5-identical slot layout (vtσ bf16 lives in the old 384K vt slot)
    float* x    = (float*)(ws + 16384);                       // 384 KB
    short* vth  = (short*)(x + (size_t)NB*NN*NC);             // 192 KB used of 384 KB slot
    float* qc   = x + 2*(size_t)NB*NN*NC;                     // 192 KB
    float* kw1  = qc + (size_t)NB*NN*NAH;                     // 192 KB
    float* hcf  = kw1 + (size_t)NB*NN*NAH;                    // 192 KB

    embed_kernel<<<NB*NN, 64, 0, stream>>>(coords, ce_w1, ce_b1, ce_w2, ce_b2,
                                           wq, wk, wvw, am_w1, am_b1, pm_w1, pm_w2, pm_b2, am_w2,
                                           maskp, x, vth, qc, kw1, hcf, maskw, w12T, peT, a2P);
    attn_kernel<<<NB*NN/2, 256, 0, stream>>>(pm_b1, out_w, out_b,
                                             x, vth, qc, kw1, hcf,
                                             maskw, w12T, peT, a2P,
                                             (float*)d_out);
}

// Round 15
// 45.668 us; speedup vs baseline: 1.2471x; 1.0825x over previous
//
#include <hip/hip_runtime.h>
#include <hip/hip_bf16.h>

#define NB 2
#define NN 768
#define NC 64
#define NPH 32
#define NAH 32
#define NEGV -1e9f
#define LOG2E 1.4426950408889634f

typedef __attribute__((ext_vector_type(8))) short bf16x8;
typedef __attribute__((ext_vector_type(4))) float f32x4;

__device__ __forceinline__ short f2bf(float f) {
    unsigned u = __builtin_bit_cast(unsigned, f);
    u = (u + 0x7FFFu + ((u >> 16) & 1u)) >> 16;
    return (short)u;
}

// packed 2xbf16 convert (RNE), 1 instruction for 2 values
__device__ __forceinline__ unsigned cvt_pk_bf16(float lo, float hi) {
    unsigned r;
    asm("v_cvt_pk_bf16_f32 %0, %1, %2" : "=v"(r) : "v"(lo), "v"(hi));
    return r;
}

__device__ __forceinline__ float bflo(unsigned u) { return __builtin_bit_cast(float, u << 16); }
__device__ __forceinline__ float bfhi(unsigned u) { return __builtin_bit_cast(float, u & 0xffff0000u); }

// async DMA: global (per-lane addr) -> LDS (wave-uniform base + lane*16). Zero VGPR cost.
__device__ __forceinline__ void gload_lds16(const void* g, void* l) {
    __builtin_amdgcn_global_load_lds(
        (const __attribute__((address_space(1))) unsigned int*)g,
        (__attribute__((address_space(3))) unsigned int*)l,
        16, 0, 0);
}

// ---------------- Kernel 1: x = MLP(coords); lane-packed bf16 vtσ(+pm_b2); qc; kW1(f32);
//                  hc = coords@pm_w1; packed mask bits; transposed bf16 weight tables ----------------
__global__ __launch_bounds__(64)
void embed_kernel(const float* __restrict__ coords,
                  const float* __restrict__ ce_w1, const float* __restrict__ ce_b1,
                  const float* __restrict__ ce_w2, const float* __restrict__ ce_b2,
                  const float* __restrict__ wq, const float* __restrict__ wk,
                  const float* __restrict__ wv,
                  const float* __restrict__ am_w1, const float* __restrict__ am_b1,
                  const float* __restrict__ pm_w1,
                  const float* __restrict__ pm_w2, const float* __restrict__ pm_b2,
                  const float* __restrict__ am_w2,
                  const void* __restrict__ maskp,
                  float* __restrict__ x, short* __restrict__ vth,
                  float* __restrict__ qc, float* __restrict__ kw1,
                  float* __restrict__ hcf,
                  unsigned long long* __restrict__ maskw,
                  short* __restrict__ w12T, short* __restrict__ peT,
                  short* __restrict__ a2P)
{
    const int row = blockIdx.x;   // b*N + n
    const int c = threadIdx.x;    // channel
    __shared__ float h1[NC];
    __shared__ float xs[NC];
    __shared__ float qs[NC];
    __shared__ float ks[NC];
    __shared__ int cnt;
    if (c == 0) cnt = 0;
    float p0 = coords[row*3+0], p1 = coords[row*3+1], p2 = coords[row*3+2];
    // hc = coords @ pm_w1 (no bias; b1 re-added for the i-side in attn)
    if (c < NPH) {
        float hcv = fmaf(p0, pm_w1[c], fmaf(p1, pm_w1[NPH+c], p2 * pm_w1[2*NPH+c]));
        hcf[row*NPH + c] = hcv;
    }
    float h = fmaf(p0, ce_w1[c], fmaf(p1, ce_w1[NC+c], fmaf(p2, ce_w1[2*NC+c], ce_b1[c])));
    h1[c] = fmaxf(h, 0.f);
    __syncthreads();
    float acc = ce_b2[c];
    for (int d = 0; d < NC; ++d) acc = fmaf(h1[d], ce_w2[d*NC+c], acc);
    xs[c] = acc;
    x[row*NC+c] = acc;
    __syncthreads();
    float aq = 0.f, ak = 0.f, av = 0.f;
    for (int d = 0; d < NC; ++d) {
        float xv = xs[d];
        aq = fmaf(xv, wq[d*NC+c], aq);
        ak = fmaf(xv, wk[d*NC+c], ak);
        av = fmaf(xv, wv[d*NC+c], av);
    }
    qs[c] = aq; ks[c] = ak;
    // lane-packed bf16 vtσ: value (j-local jj, channel c) of tile -> [lane = (jj>>2)*16 + (c&15)]
    //   [k = (c>>4)*4 + (jj&3)]; reader lane (kgp,cl) k (nt,r) gets vt[c=nt*16+cl][j=kgp*4+r]
    {
        int bb = row / NN, nn = row - bb*NN;
        int tile = nn >> 4, jj = nn & 15;
        int lp = ((jj >> 2) << 4) | (c & 15);
        int kp = ((c >> 4) << 2) | (jj & 3);
        vth[((size_t)bb*48 + tile)*1024 + lp*16 + kp] = f2bf(av + pm_b2[c]);
    }
    __syncthreads();
    if (c < NAH) {
        // qc = (q + pm_b2) @ am_w1 + am_b1
        float a2 = am_b1[c];
        for (int d = 0; d < NC; ++d) a2 = fmaf(qs[d] + pm_b2[d], am_w1[d*NAH+c], a2);
        qc[row*NAH+c] = a2;
    } else {
        int hh = c - NAH;
        float a2 = 0.f;
        for (int d = 0; d < NC; ++d) a2 = fmaf(ks[d], am_w1[d*NAH+hh], a2);
        kw1[row*NAH+hh] = a2;
    }

    if (row == 0) {
        // mask dtype detection (bool-as-uint8 ~1382 bytes==1; int32 <=384), then bit-pack
        const unsigned char* mB = (const unsigned char*)maskp;
        const int* mI = (const int*)maskp;
        int local = 0;
        for (int t = c; t < NB*NN; t += NC) local += (mB[t] == 1) ? 1 : 0;
        atomicAdd(&cnt, local);
        __syncthreads();
        int isByte = (cnt > 800);
        if (c < 24) {
            unsigned long long bits = 0ull;
            for (int e = 0; e < 64; ++e) {
                int j = c*64 + e;
                int mv = isByte ? (int)mB[j] : mI[j];
                bits |= (unsigned long long)((mv != 0) ? 1 : 0) << e;
            }
            maskw[c] = bits;
        }
    }
    if (row >= 1 && row <= 8) {
        // w12T[c2*32 + p] = W12[p][c2], W12 = pm_w2 @ am_w1 (32x32), bf16
        int ri = row - 1;
        #pragma unroll
        for (int t = 0; t < 2; ++t) {
            int o = ri*128 + c*2 + t;
            int c2 = o >> 5, p = o & 31;
            float a2 = 0.f;
            for (int d = 0; d < NC; ++d) a2 = fmaf(pm_w2[p*NC+d], am_w1[d*NAH+c2], a2);
            w12T[o] = f2bf(a2);
        }
    }
    if (row >= 9 && row <= 16) {
        // peT[cc*32 + h] = pm_w2[h][cc], bf16
        int ri = row - 9;
        #pragma unroll
        for (int t = 0; t < 4; ++t) {
            int o = ri*256 + c*4 + t;
            int cc = o >> 5, hh = o & 31;
            peT[o] = f2bf(pm_w2[hh*NC + cc]);
        }
    }
    if (row >= 17 && row <= 24) {
        // a2P[cc*32 + s] = am_w2[h(s)][cc]*log2e, h(s) = ((s&7)>>2)*16 + (s>>3)*4 + (s&3)
        int ri = row - 17;
        #pragma unroll
        for (int t = 0; t < 4; ++t) {
            int o = ri*256 + c*4 + t;
            int cc = o >> 5, s = o & 31;
            int e = s & 7, kg = s >> 3;
            int hh = ((e >> 2) << 4) + kg*4 + (e & 3);
            a2P[o] = f2bf(am_w2[hh*NC + cc] * LOG2E);
        }
    }
}

// ---------------- Kernel 2: r12 structure: full DMA staging via global_load_lds
//                  double-buffer, exact vmcnt(6), mask in logits C-init ----------------
// Block = 4 waves, handles i-pair (2*blockIdx.x, +1). Wave w does j-tiles w, w+4, ... (12).
__global__ __launch_bounds__(256, 3)
void attn_kernel(const float* __restrict__ pm_b1,
                 const float* __restrict__ out_w, const float* __restrict__ out_b,
                 const float* __restrict__ xg,
                 const short* __restrict__ vth,
                 const float* __restrict__ qcg, const float* __restrict__ kw1g,
                 const float* __restrict__ hcfg,
                 const unsigned long long* __restrict__ maskw,
                 const short* __restrict__ w12T, const short* __restrict__ peT,
                 const short* __restrict__ a2P,
                 float* __restrict__ out)
{
    const int tid  = threadIdx.x;
    const int wv   = tid >> 6;
    const int lane = tid & 63;
    const int cl   = lane & 15;         // A/B-frag row/col
    const int kgp  = lane >> 4;         // k-group

    const int bi0 = blockIdx.x * 2;     // first of the i-pair (same b: NN even)
    const int b   = bi0 / NN;

    // [wave][buf]: kv0|kv1|vv0|vv1|hj0|hj1, 1KB each = 6KB/buf; 48KB total.
    __shared__ __align__(16) char stage[4][2][6144];
    // comb/agg alias the stage region (dead after the main loop; barrier before reuse)
    float* combp = (float*)&stage[0][0][0];   // [2][2][4][NC] = 1024 floats
    float* aggp  = combp + 1024;              // [2][NC] = 128 floats

    // ---- weight fragments: contiguous b128 loads from transposed tables ----
    bf16x8 bPE[4], bW12[2], bA2[4];
    #pragma unroll
    for (int nt = 0; nt < 4; ++nt) bPE[nt] = *(const bf16x8*)(peT + (nt*16+cl)*NPH + kgp*8);
    #pragma unroll
    for (int ht = 0; ht < 2; ++ht) bW12[ht] = *(const bf16x8*)(w12T + (ht*16+cl)*NPH + kgp*8);
    #pragma unroll
    for (int nt = 0; nt < 4; ++nt) bA2[nt] = *(const bf16x8*)(a2P + (nt*16+cl)*NPH + kgp*8);

    // ---- per-i state: qc C-init and hc_i + b1 ----
    f32x4 qcC[2][2], hciA[2][2];
    {
        f32x4 b1a = *(const f32x4*)(pm_b1 + kgp*8);
        f32x4 b1b = *(const f32x4*)(pm_b1 + kgp*8 + 4);
        #pragma unroll
        for (int g = 0; g < 2; ++g) {
            #pragma unroll
            for (int ht = 0; ht < 2; ++ht)
                qcC[g][ht] = *(const f32x4*)(qcg + (size_t)(bi0+g)*NAH + ht*16 + kgp*4);
            f32x4 h0 = *(const f32x4*)(hcfg + (size_t)(bi0+g)*NPH + kgp*8);
            f32x4 h1 = *(const f32x4*)(hcfg + (size_t)(bi0+g)*NPH + kgp*8 + 4);
            hciA[g][0] = h0 + b1a;
            hciA[g][1] = h1 + b1b;
        }
    }

    const int maskBase = b * NN;
    const float* krow = kw1g + (size_t)(maskBase + wv*16 + cl) * NAH + kgp*4;
    const short* vvp  = vth + ((size_t)b*48 + wv)*1024 + (size_t)lane*16;
    const float* hjr  = hcfg + (size_t)(maskBase + wv*16 + cl) * NPH + kgp*8;
    const unsigned long long* mwp = maskw + b*12;
    const int shft = wv*16 + kgp*4;

    float l_[2][4], ac_[2][4];
    #pragma unroll
    for (int g = 0; g < 2; ++g)
        #pragma unroll
        for (int nt = 0; nt < 4; ++nt) { l_[g][nt] = 0.f; ac_[g][nt] = 0.f; }

    // issue tile t's 6 DMA loads into buf (per-lane global src, linear lane*16 LDS dst)
    auto stage_tile = [&](int t, int buf) {
        char* base = &stage[wv][buf][0];
        const float* kr = krow + (size_t)t*2048;   // 64 rows * NAH floats / tile-group
        const short* vs = vvp  + (size_t)t*4096;   // 4*1024 shorts
        const float* hr = hjr  + (size_t)t*2048;   // 64 rows * NPH floats
        gload_lds16(kr,      base);
        gload_lds16(kr + 16, base + 1024);
        gload_lds16(vs,      base + 2048);
        gload_lds16(vs + 8,  base + 3072);
        gload_lds16(hr,      base + 4096);
        gload_lds16(hr + 4,  base + 5120);
    };

    stage_tile(0, 0);

    for (int p = 0; p < 12; ++p) {
        // prefetch next tile, then wait only for tile p (next's 6 stay in flight)
        if (p < 11) {
            stage_tile(p + 1, (p + 1) & 1);
            asm volatile("s_waitcnt vmcnt(6)" ::: "memory");
        } else {
            asm volatile("s_waitcnt vmcnt(0)" ::: "memory");
        }

        // read back this wave's private slots (stride-1 lane*16: conflict-free)
        const char* base = &stage[wv][p & 1][0];
        f32x4 kv0  = *(const f32x4*)(base + (size_t)lane*16);
        f32x4 kv1  = *(const f32x4*)(base + 1024 + (size_t)lane*16);
        bf16x8 vv0 = *(const bf16x8*)(base + 2048 + (size_t)lane*16);
        bf16x8 vv1 = *(const bf16x8*)(base + 3072 + (size_t)lane*16);
        f32x4 hj0  = *(const f32x4*)(base + 4096 + (size_t)lane*16);
        f32x4 hj1  = *(const f32x4*)(base + 5120 + (size_t)lane*16);
        unsigned bits4 = (unsigned)(mwp[p] >> shft) & 0xFu;

        // mask as logits C-init: C row r (= j = kgp*4+r) masked -> -1e9; exp2 -> exact 0
        f32x4 maskC;
        #pragma unroll
        for (int r = 0; r < 4; ++r) maskC[r] = (bits4 & (1u << r)) ? 0.f : NEGV;

        // unpack vtσ -> f32 C-init (v_j + pm_b2)
        const unsigned* vq0 = (const unsigned*)&vv0;
        const unsigned* vq1 = (const unsigned*)&vv1;
        f32x4 vA[4];
        vA[0][0]=bflo(vq0[0]); vA[0][1]=bfhi(vq0[0]); vA[0][2]=bflo(vq0[1]); vA[0][3]=bfhi(vq0[1]);
        vA[1][0]=bflo(vq0[2]); vA[1][1]=bfhi(vq0[2]); vA[1][2]=bflo(vq0[3]); vA[1][3]=bfhi(vq0[3]);
        vA[2][0]=bflo(vq1[0]); vA[2][1]=bfhi(vq1[0]); vA[2][2]=bflo(vq1[1]); vA[2][3]=bfhi(vq1[1]);
        vA[3][0]=bflo(vq1[2]); vA[3][1]=bfhi(vq1[2]); vA[3][2]=bflo(vq1[3]); vA[3][3]=bfhi(vq1[3]);

        // ---- two independent i-chains over the shared tile ----
        #pragma unroll
        for (int g = 0; g < 2; ++g) {
            // hp = relu(hc_i + b1 - hc_j)
            float hv[8];
            #pragma unroll
            for (int e = 0; e < 4; ++e) {
                hv[e]   = fmaxf(hciA[g][0][e] - hj0[e], 0.f);
                hv[4+e] = fmaxf(hciA[g][1][e] - hj1[e], 0.f);
            }
            union { bf16x8 h8; unsigned u[4]; } aHP;
            #pragma unroll
            for (int p2 = 0; p2 < 4; ++p2) aHP.u[p2] = cvt_pk_bf16(hv[2*p2], hv[2*p2+1]);

            // PE + v_j (C-init = vtσ)
            f32x4 pe[4];
            #pragma unroll
            for (int nt = 0; nt < 4; ++nt)
                pe[nt] = __builtin_amdgcn_mfma_f32_16x16x32_bf16(aHP.h8, bPE[nt], vA[nt], 0, 0, 0);

            // H^T = W12^T @ hp^T + qc
            f32x4 hT[2];
            #pragma unroll
            for (int ht = 0; ht < 2; ++ht)
                hT[ht] = __builtin_amdgcn_mfma_f32_16x16x32_bf16(bW12[ht], aHP.h8, qcC[g][ht], 0, 0, 0);

            // relu(H^T - kW1), repack as logits A-frag (slot e = ht*4+r)
            float f8[8];
            #pragma unroll
            for (int r = 0; r < 4; ++r) {
                f8[r]   = fmaxf(hT[0][r] - kv0[r], 0.f);
                f8[4+r] = fmaxf(hT[1][r] - kv1[r], 0.f);
            }
            union { bf16x8 h8; unsigned u[4]; } aH;
            #pragma unroll
            for (int p2 = 0; p2 < 4; ++p2) aH.u[p2] = cvt_pk_bf16(f8[2*p2], f8[2*p2+1]);

            // logits (log2-domain, mask pre-added via C-init) + maxless exp2 accumulation
            #pragma unroll
            for (int nt = 0; nt < 4; ++nt) {
                f32x4 atl = __builtin_amdgcn_mfma_f32_16x16x32_bf16(aH.h8, bA2[nt], maskC, 0, 0, 0);
                #pragma unroll
                for (int r = 0; r < 4; ++r) {
                    float pp = __builtin_amdgcn_exp2f(atl[r]);
                    l_[g][nt] += pp;
                    ac_[g][nt] = fmaf(pp, pe[nt][r], ac_[g][nt]);
                }
            }
        }
    }

    // combine the 4 row-group streams within the wave (plain sums)
    #pragma unroll
    for (int st = 16; st <= 32; st <<= 1) {
        #pragma unroll
        for (int g = 0; g < 2; ++g)
            #pragma unroll
            for (int nt = 0; nt < 4; ++nt) {
                l_[g][nt]  += __shfl_xor(l_[g][nt], st);
                ac_[g][nt] += __shfl_xor(ac_[g][nt], st);
            }
    }

    __syncthreads();   // all waves done with stage -> safe to reuse as comb/agg

    if (lane < 16) {
        #pragma unroll
        for (int g = 0; g < 2; ++g)
            #pragma unroll
            for (int nt = 0; nt < 4; ++nt) {
                combp[((0*2+g)*4 + wv)*NC + nt*16+lane] = l_[g][nt];
                combp[((1*2+g)*4 + wv)*NC + nt*16+lane] = ac_[g][nt];
            }
    }
    __syncthreads();

    if (tid < 128) {
        int g = tid >> 6, c = tid & 63;
        float lt = 0.f, at2 = 0.f;
        #pragma unroll
        for (int w = 0; w < 4; ++w) {
            lt  += combp[((0*2+g)*4 + w)*NC + c];
            at2 += combp[((1*2+g)*4 + w)*NC + c];
        }
        aggp[g*NC + c] = at2 / lt;
    }
    __syncthreads();

    if (tid < 128) {
        int g = tid >> 6, c = tid & 63;
        int bi2 = bi0 + g;
        float o = out_b[c] + xg[(size_t)bi2*NC + c];
        for (int d = 0; d < NC; ++d) o = fmaf(aggp[g*NC + d], out_w[d*NC + c], o);
        out[(size_t)bi2*NC + c] = o;
    }
}

extern "C" void kernel_launch(void* const* d_in, const int* in_sizes, int n_in,
                              void* d_out, int out_size, void* d_ws, size_t ws_size,
                              hipStream_t stream) {
    const float* coords = (const float*)d_in[0];
    const void*  maskp  = d_in[1];
    const float* ce_w1  = (const float*)d_in[2];
    const float* ce_b1  = (const float*)d_in[3];
    const float* ce_w2  = (const float*)d_in[4];
    const float* ce_b2  = (const float*)d_in[5];
    const float* wq     = (const float*)d_in[6];
    const float* wk     = (const float*)d_in[7];
    const float* wvw    = (const float*)d_in[8];
    const float* pm_w1  = (const float*)d_in[9];
    const float* pm_b1  = (const float*)d_in[10];
    const float* pm_w2  = (const float*)d_in[11];
    const float* pm_b2  = (const float*)d_in[12];
    const float* am_w1  = (const float*)d_in[13];
    const float* am_b1  = (const float*)d_in[14];
    const float* am_w2  = (const float*)d_in[15];
    // d_in[16] = am_b2: cancels in per-channel softmax, unused
    const float* out_w  = (const float*)d_in[17];
    const float* out_b  = (const float*)d_in[18];

    char* ws = (char*)d_ws;
    unsigned long long* maskw = (unsigned long long*)ws;      // 24 * 8 B
    short* w12T = (short*)(ws + 256);                         // 2 KB
    short* peT  = (short*)(ws + 4096);                        // 4 KB
    short* a2P  = (short*)(ws + 8192);                        // 4 KB
    // r5-identical slot layout (vtσ bf16 lives in the old 384K vt slot)
    float* x    = (float*)(ws + 16384);                       // 384 KB
    short* vth  = (short*)(x + (size_t)NB*NN*NC);             // 192 KB used of 384 KB slot
    float* qc   = x + 2*(size_t)NB*NN*NC;                     // 192 KB
    float* kw1  = qc + (size_t)NB*NN*NAH;                     // 192 KB
    float* hcf  = kw1 + (size_t)NB*NN*NAH;                    // 192 KB

    embed_kernel<<<NB*NN, 64, 0, stream>>>(coords, ce_w1, ce_b1, ce_w2, ce_b2,
                                           wq, wk, wvw, am_w1, am_b1, pm_w1, pm_w2, pm_b2, am_w2,
                                           maskp, x, vth, qc, kw1, hcf, maskw, w12T, peT, a2P);
    attn_kernel<<<NB*NN/2, 256, 0, stream>>>(pm_b1, out_w, out_b,
                                             x, vth, qc, kw1, hcf,
                                             maskw, w12T, peT, a2P,
                                             (float*)d_out);
}

// Round 16
// 44.956 us; speedup vs baseline: 1.2669x; 1.0158x over previous
//
#include <hip/hip_runtime.h>
#include <hip/hip_bf16.h>

#define NB 2
#define NN 768
#define NC 64
#define NPH 32
#define NAH 32
#define NEGV -1e9f
#define LOG2E 1.4426950408889634f

typedef __attribute__((ext_vector_type(8))) short bf16x8;
typedef __attribute__((ext_vector_type(4))) float f32x4;

__device__ __forceinline__ short f2bf(float f) {
    unsigned u = __builtin_bit_cast(unsigned, f);
    u = (u + 0x7FFFu + ((u >> 16) & 1u)) >> 16;
    return (short)u;
}

// packed 2xbf16 convert (RNE), 1 instruction for 2 values
__device__ __forceinline__ unsigned cvt_pk_bf16(float lo, float hi) {
    unsigned r;
    asm("v_cvt_pk_bf16_f32 %0, %1, %2" : "=v"(r) : "v"(lo), "v"(hi));
    return r;
}

__device__ __forceinline__ float bflo(unsigned u) { return __builtin_bit_cast(float, u << 16); }
__device__ __forceinline__ float bfhi(unsigned u) { return __builtin_bit_cast(float, u & 0xffff0000u); }

// async DMA: global (per-lane addr) -> LDS (wave-uniform base + lane*16). Zero VGPR cost.
__device__ __forceinline__ void gload_lds16(const void* g, void* l) {
    __builtin_amdgcn_global_load_lds(
        (const __attribute__((address_space(1))) unsigned int*)g,
        (__attribute__((address_space(3))) unsigned int*)l,
        16, 0, 0);
}

// ---------------- Kernel 1: x = MLP(coords); lane-packed bf16 vtσ(+pm_b2); qc; kW1(f32);
//                  hc = coords@pm_w1; packed mask bits; transposed bf16 weight tables ----------------
__global__ __launch_bounds__(64)
void embed_kernel(const float* __restrict__ coords,
                  const float* __restrict__ ce_w1, const float* __restrict__ ce_b1,
                  const float* __restrict__ ce_w2, const float* __restrict__ ce_b2,
                  const float* __restrict__ wq, const float* __restrict__ wk,
                  const float* __restrict__ wv,
                  const float* __restrict__ am_w1, const float* __restrict__ am_b1,
                  const float* __restrict__ pm_w1,
                  const float* __restrict__ pm_w2, const float* __restrict__ pm_b2,
                  const float* __restrict__ am_w2,
                  const void* __restrict__ maskp,
                  float* __restrict__ x, short* __restrict__ vth,
                  float* __restrict__ qc, float* __restrict__ kw1,
                  float* __restrict__ hcf,
                  unsigned long long* __restrict__ maskw,
                  short* __restrict__ w12T, short* __restrict__ peT,
                  short* __restrict__ a2P)
{
    const int row = blockIdx.x;   // b*N + n
    const int c = threadIdx.x;    // channel
    __shared__ float h1[NC];
    __shared__ float xs[NC];
    __shared__ float qs[NC];
    __shared__ float ks[NC];
    __shared__ int cnt;
    if (c == 0) cnt = 0;
    float p0 = coords[row*3+0], p1 = coords[row*3+1], p2 = coords[row*3+2];
    // hc = coords @ pm_w1 (no bias; b1 re-added for the i-side in attn)
    if (c < NPH) {
        float hcv = fmaf(p0, pm_w1[c], fmaf(p1, pm_w1[NPH+c], p2 * pm_w1[2*NPH+c]));
        hcf[row*NPH + c] = hcv;
    }
    float h = fmaf(p0, ce_w1[c], fmaf(p1, ce_w1[NC+c], fmaf(p2, ce_w1[2*NC+c], ce_b1[c])));
    h1[c] = fmaxf(h, 0.f);
    __syncthreads();
    float acc = ce_b2[c];
    for (int d = 0; d < NC; ++d) acc = fmaf(h1[d], ce_w2[d*NC+c], acc);
    xs[c] = acc;
    x[row*NC+c] = acc;
    __syncthreads();
    float aq = 0.f, ak = 0.f, av = 0.f;
    for (int d = 0; d < NC; ++d) {
        float xv = xs[d];
        aq = fmaf(xv, wq[d*NC+c], aq);
        ak = fmaf(xv, wk[d*NC+c], ak);
        av = fmaf(xv, wv[d*NC+c], av);
    }
    qs[c] = aq; ks[c] = ak;
    // lane-packed bf16 vtσ: value (j-local jj, channel c) of tile -> [lane = (jj>>2)*16 + (c&15)]
    //   [k = (c>>4)*4 + (jj&3)]; reader lane (kgp,cl) k (nt,r) gets vt[c=nt*16+cl][j=kgp*4+r]
    {
        int bb = row / NN, nn = row - bb*NN;
        int tile = nn >> 4, jj = nn & 15;
        int lp = ((jj >> 2) << 4) | (c & 15);
        int kp = ((c >> 4) << 2) | (jj & 3);
        vth[((size_t)bb*48 + tile)*1024 + lp*16 + kp] = f2bf(av + pm_b2[c]);
    }
    __syncthreads();
    if (c < NAH) {
        // qc = (q + pm_b2) @ am_w1 + am_b1
        float a2 = am_b1[c];
        for (int d = 0; d < NC; ++d) a2 = fmaf(qs[d] + pm_b2[d], am_w1[d*NAH+c], a2);
        qc[row*NAH+c] = a2;
    } else {
        int hh = c - NAH;
        float a2 = 0.f;
        for (int d = 0; d < NC; ++d) a2 = fmaf(ks[d], am_w1[d*NAH+hh], a2);
        kw1[row*NAH+hh] = a2;
    }

    if (row == 0) {
        // mask dtype detection (bool-as-uint8 ~1382 bytes==1; int32 <=384), then bit-pack
        const unsigned char* mB = (const unsigned char*)maskp;
        const int* mI = (const int*)maskp;
        int local = 0;
        for (int t = c; t < NB*NN; t += NC) local += (mB[t] == 1) ? 1 : 0;
        atomicAdd(&cnt, local);
        __syncthreads();
        int isByte = (cnt > 800);
        if (c < 24) {
            unsigned long long bits = 0ull;
            for (int e = 0; e < 64; ++e) {
                int j = c*64 + e;
                int mv = isByte ? (int)mB[j] : mI[j];
                bits |= (unsigned long long)((mv != 0) ? 1 : 0) << e;
            }
            maskw[c] = bits;
        }
    }
    if (row >= 1 && row <= 8) {
        // w12T[c2*32 + p] = W12[p][c2], W12 = pm_w2 @ am_w1 (32x32), bf16
        int ri = row - 1;
        #pragma unroll
        for (int t = 0; t < 2; ++t) {
            int o = ri*128 + c*2 + t;
            int c2 = o >> 5, p = o & 31;
            float a2 = 0.f;
            for (int d = 0; d < NC; ++d) a2 = fmaf(pm_w2[p*NC+d], am_w1[d*NAH+c2], a2);
            w12T[o] = f2bf(a2);
        }
    }
    if (row >= 9 && row <= 16) {
        // peT[cc*32 + h] = pm_w2[h][cc], bf16
        int ri = row - 9;
        #pragma unroll
        for (int t = 0; t < 4; ++t) {
            int o = ri*256 + c*4 + t;
            int cc = o >> 5, hh = o & 31;
            peT[o] = f2bf(pm_w2[hh*NC + cc]);
        }
    }
    if (row >= 17 && row <= 24) {
        // a2P[cc*32 + s] = am_w2[h(s)][cc]*log2e, h(s) = ((s&7)>>2)*16 + (s>>3)*4 + (s&3)
        int ri = row - 17;
        #pragma unroll
        for (int t = 0; t < 4; ++t) {
            int o = ri*256 + c*4 + t;
            int cc = o >> 5, s = o & 31;
            int e = s & 7, kg = s >> 3;
            int hh = ((e >> 2) << 4) + kg*4 + (e & 3);
            a2P[o] = f2bf(am_w2[hh*NC + cc] * LOG2E);
        }
    }
}

// ---------------- Kernel 2: r12 structure (full DMA staging, exact vmcnt(6), mask in
//                  logits C-init) + s_setprio(1) around the per-tile compute phase ----------------
// Block = 4 waves, handles i-pair (2*blockIdx.x, +1). Wave w does j-tiles w, w+4, ... (12).
__global__ __launch_bounds__(256, 3)
void attn_kernel(const float* __restrict__ pm_b1,
                 const float* __restrict__ out_w, const float* __restrict__ out_b,
                 const float* __restrict__ xg,
                 const short* __restrict__ vth,
                 const float* __restrict__ qcg, const float* __restrict__ kw1g,
                 const float* __restrict__ hcfg,
                 const unsigned long long* __restrict__ maskw,
                 const short* __restrict__ w12T, const short* __restrict__ peT,
                 const short* __restrict__ a2P,
                 float* __restrict__ out)
{
    const int tid  = threadIdx.x;
    const int wv   = tid >> 6;
    const int lane = tid & 63;
    const int cl   = lane & 15;         // A/B-frag row/col
    const int kgp  = lane >> 4;         // k-group

    const int bi0 = blockIdx.x * 2;     // first of the i-pair (same b: NN even)
    const int b   = bi0 / NN;

    // [wave][buf]: kv0|kv1|vv0|vv1|hj0|hj1, 1KB each = 6KB/buf; 48KB total.
    __shared__ __align__(16) char stage[4][2][6144];
    // comb/agg alias the stage region (dead after the main loop; barrier before reuse)
    float* combp = (float*)&stage[0][0][0];   // [2][2][4][NC] = 1024 floats
    float* aggp  = combp + 1024;              // [2][NC] = 128 floats

    // ---- weight fragments: contiguous b128 loads from transposed tables ----
    bf16x8 bPE[4], bW12[2], bA2[4];
    #pragma unroll
    for (int nt = 0; nt < 4; ++nt) bPE[nt] = *(const bf16x8*)(peT + (nt*16+cl)*NPH + kgp*8);
    #pragma unroll
    for (int ht = 0; ht < 2; ++ht) bW12[ht] = *(const bf16x8*)(w12T + (ht*16+cl)*NPH + kgp*8);
    #pragma unroll
    for (int nt = 0; nt < 4; ++nt) bA2[nt] = *(const bf16x8*)(a2P + (nt*16+cl)*NPH + kgp*8);

    // ---- per-i state: qc C-init and hc_i + b1 ----
    f32x4 qcC[2][2], hciA[2][2];
    {
        f32x4 b1a = *(const f32x4*)(pm_b1 + kgp*8);
        f32x4 b1b = *(const f32x4*)(pm_b1 + kgp*8 + 4);
        #pragma unroll
        for (int g = 0; g < 2; ++g) {
            #pragma unroll
            for (int ht = 0; ht < 2; ++ht)
                qcC[g][ht] = *(const f32x4*)(qcg + (size_t)(bi0+g)*NAH + ht*16 + kgp*4);
            f32x4 h0 = *(const f32x4*)(hcfg + (size_t)(bi0+g)*NPH + kgp*8);
            f32x4 h1 = *(const f32x4*)(hcfg + (size_t)(bi0+g)*NPH + kgp*8 + 4);
            hciA[g][0] = h0 + b1a;
            hciA[g][1] = h1 + b1b;
        }
    }

    const int maskBase = b * NN;
    const float* krow = kw1g + (size_t)(maskBase + wv*16 + cl) * NAH + kgp*4;
    const short* vvp  = vth + ((size_t)b*48 + wv)*1024 + (size_t)lane*16;
    const float* hjr  = hcfg + (size_t)(maskBase + wv*16 + cl) * NPH + kgp*8;
    const unsigned long long* mwp = maskw + b*12;
    const int shft = wv*16 + kgp*4;

    float l_[2][4], ac_[2][4];
    #pragma unroll
    for (int g = 0; g < 2; ++g)
        #pragma unroll
        for (int nt = 0; nt < 4; ++nt) { l_[g][nt] = 0.f; ac_[g][nt] = 0.f; }

    // issue tile t's 6 DMA loads into buf (per-lane global src, linear lane*16 LDS dst)
    auto stage_tile = [&](int t, int buf) {
        char* base = &stage[wv][buf][0];
        const float* kr = krow + (size_t)t*2048;   // 64 rows * NAH floats / tile-group
        const short* vs = vvp  + (size_t)t*4096;   // 4*1024 shorts
        const float* hr = hjr  + (size_t)t*2048;   // 64 rows * NPH floats
        gload_lds16(kr,      base);
        gload_lds16(kr + 16, base + 1024);
        gload_lds16(vs,      base + 2048);
        gload_lds16(vs + 8,  base + 3072);
        gload_lds16(hr,      base + 4096);
        gload_lds16(hr + 4,  base + 5120);
    };

    stage_tile(0, 0);

    for (int p = 0; p < 12; ++p) {
        // prefetch next tile, then wait only for tile p (next's 6 stay in flight)
        if (p < 11) {
            stage_tile(p + 1, (p + 1) & 1);
            asm volatile("s_waitcnt vmcnt(6)" ::: "memory");
        } else {
            asm volatile("s_waitcnt vmcnt(0)" ::: "memory");
        }

        // read back this wave's private slots (stride-1 lane*16: conflict-free)
        const char* base = &stage[wv][p & 1][0];
        f32x4 kv0  = *(const f32x4*)(base + (size_t)lane*16);
        f32x4 kv1  = *(const f32x4*)(base + 1024 + (size_t)lane*16);
        bf16x8 vv0 = *(const bf16x8*)(base + 2048 + (size_t)lane*16);
        bf16x8 vv1 = *(const bf16x8*)(base + 3072 + (size_t)lane*16);
        f32x4 hj0  = *(const f32x4*)(base + 4096 + (size_t)lane*16);
        f32x4 hj1  = *(const f32x4*)(base + 5120 + (size_t)lane*16);
        unsigned bits4 = (unsigned)(mwp[p] >> shft) & 0xFu;

        // mask as logits C-init: C row r (= j = kgp*4+r) masked -> -1e9; exp2 -> exact 0
        f32x4 maskC;
        #pragma unroll
        for (int r = 0; r < 4; ++r) maskC[r] = (bits4 & (1u << r)) ? 0.f : NEGV;

        // unpack vtσ -> f32 C-init (v_j + pm_b2)
        const unsigned* vq0 = (const unsigned*)&vv0;
        const unsigned* vq1 = (const unsigned*)&vv1;
        f32x4 vA[4];
        vA[0][0]=bflo(vq0[0]); vA[0][1]=bfhi(vq0[0]); vA[0][2]=bflo(vq0[1]); vA[0][3]=bfhi(vq0[1]);
        vA[1][0]=bflo(vq0[2]); vA[1][1]=bfhi(vq0[2]); vA[1][2]=bflo(vq0[3]); vA[1][3]=bfhi(vq0[3]);
        vA[2][0]=bflo(vq1[0]); vA[2][1]=bfhi(vq1[0]); vA[2][2]=bflo(vq1[1]); vA[2][3]=bfhi(vq1[1]);
        vA[3][0]=bflo(vq1[2]); vA[3][1]=bfhi(vq1[2]); vA[3][2]=bflo(vq1[3]); vA[3][3]=bfhi(vq1[3]);

        // ---- compute phase at elevated priority: waves with a ready MFMA/VALU chain
        //      win issue arbitration over waves still in readback (T5, m191 regime) ----
        __builtin_amdgcn_s_setprio(1);
        #pragma unroll
        for (int g = 0; g < 2; ++g) {
            // hp = relu(hc_i + b1 - hc_j)
            float hv[8];
            #pragma unroll
            for (int e = 0; e < 4; ++e) {
                hv[e]   = fmaxf(hciA[g][0][e] - hj0[e], 0.f);
                hv[4+e] = fmaxf(hciA[g][1][e] - hj1[e], 0.f);
            }
            union { bf16x8 h8; unsigned u[4]; } aHP;
            #pragma unroll
            for (int p2 = 0; p2 < 4; ++p2) aHP.u[p2] = cvt_pk_bf16(hv[2*p2], hv[2*p2+1]);

            // PE + v_j (C-init = vtσ)
            f32x4 pe[4];
            #pragma unroll
            for (int nt = 0; nt < 4; ++nt)
                pe[nt] = __builtin_amdgcn_mfma_f32_16x16x32_bf16(aHP.h8, bPE[nt], vA[nt], 0, 0, 0);

            // H^T = W12^T @ hp^T + qc
            f32x4 hT[2];
            #pragma unroll
            for (int ht = 0; ht < 2; ++ht)
                hT[ht] = __builtin_amdgcn_mfma_f32_16x16x32_bf16(bW12[ht], aHP.h8, qcC[g][ht], 0, 0, 0);

            // relu(H^T - kW1), repack as logits A-frag (slot e = ht*4+r)
            float f8[8];
            #pragma unroll
            for (int r = 0; r < 4; ++r) {
                f8[r]   = fmaxf(hT[0][r] - kv0[r], 0.f);
                f8[4+r] = fmaxf(hT[1][r] - kv1[r], 0.f);
            }
            union { bf16x8 h8; unsigned u[4]; } aH;
            #pragma unroll
            for (int p2 = 0; p2 < 4; ++p2) aH.u[p2] = cvt_pk_bf16(f8[2*p2], f8[2*p2+1]);

            // logits (log2-domain, mask pre-added via C-init) + maxless exp2 accumulation
            #pragma unroll
            for (int nt = 0; nt < 4; ++nt) {
                f32x4 atl = __builtin_amdgcn_mfma_f32_16x16x32_bf16(aH.h8, bA2[nt], maskC, 0, 0, 0);
                #pragma unroll
                for (int r = 0; r < 4; ++r) {
                    float pp = __builtin_amdgcn_exp2f(atl[r]);
                    l_[g][nt] += pp;
                    ac_[g][nt] = fmaf(pp, pe[nt][r], ac_[g][nt]);
                }
            }
        }
        __builtin_amdgcn_s_setprio(0);
    }

    // combine the 4 row-group streams within the wave (plain sums)
    #pragma unroll
    for (int st = 16; st <= 32; st <<= 1) {
        #pragma unroll
        for (int g = 0; g < 2; ++g)
            #pragma unroll
            for (int nt = 0; nt < 4; ++nt) {
                l_[g][nt]  += __shfl_xor(l_[g][nt], st);
                ac_[g][nt] += __shfl_xor(ac_[g][nt], st);
            }
    }

    __syncthreads();   // all waves done with stage -> safe to reuse as comb/agg

    if (lane < 16) {
        #pragma unroll
        for (int g = 0; g < 2; ++g)
            #pragma unroll
            for (int nt = 0; nt < 4; ++nt) {
                combp[((0*2+g)*4 + wv)*NC + nt*16+lane] = l_[g][nt];
                combp[((1*2+g)*4 + wv)*NC + nt*16+lane] = ac_[g][nt];
            }
    }
    __syncthreads();

    if (tid < 128) {
        int g = tid >> 6, c = tid & 63;
        float lt = 0.f, at2 = 0.f;
        #pragma unroll
        for (int w = 0; w < 4; ++w) {
            lt  += combp[((0*2+g)*4 + w)*NC + c];
            at2 += combp[((1*2+g)*4 + w)*NC + c];
        }
        aggp[g*NC + c] = at2 / lt;
    }
    __syncthreads();

    if (tid < 128) {
        int g = tid >> 6, c = tid & 63;
        int bi2 = bi0 + g;
        float o = out_b[c] + xg[(size_t)bi2*NC + c];
        for (int d = 0; d < NC; ++d) o = fmaf(aggp[g*NC + d], out_w[d*NC + c], o);
        out[(size_t)bi2*NC + c] = o;
    }
}

extern "C" void kernel_launch(void* const* d_in, const int* in_sizes, int n_in,
                              void* d_out, int out_size, void* d_ws, size_t ws_size,
                              hipStream_t stream) {
    const float* coords = (const float*)d_in[0];
    const void*  maskp  = d_in[1];
    const float* ce_w1  = (const float*)d_in[2];
    const float* ce_b1  = (const float*)d_in[3];
    const float* ce_w2  = (const float*)d_in[4];
    const float* ce_b2  = (const float*)d_in[5];
    const float* wq     = (const float*)d_in[6];
    const float* wk     = (const float*)d_in[7];
    const float* wvw    = (const float*)d_in[8];
    const float* pm_w1  = (const float*)d_in[9];
    const float* pm_b1  = (const float*)d_in[10];
    const float* pm_w2  = (const float*)d_in[11];
    const float* pm_b2  = (const float*)d_in[12];
    const float* am_w1  = (const float*)d_in[13];
    const float* am_b1  = (const float*)d_in[14];
    const float* am_w2  = (const float*)d_in[15];
    // d_in[16] = am_b2: cancels in per-channel softmax, unused
    const float* out_w  = (const float*)d_in[17];
    const float* out_b  = (const float*)d_in[18];

    char* ws = (char*)d_ws;
    unsigned long long* maskw = (unsigned long long*)ws;      // 24 * 8 B
    short* w12T = (short*)(ws + 256);                         // 2 KB
    short* peT  = (short*)(ws + 4096);                        // 4 KB
    short* a2P  = (short*)(ws + 8192);                        // 4 KB
    // r5-identical slot layout (vtσ bf16 lives in the old 384K vt slot)
    float* x    = (float*)(ws + 16384);                       // 384 KB
    short* vth  = (short*)(x + (size_t)NB*NN*NC);             // 192 KB used of 384 KB slot
    float* qc   = x + 2*(size_t)NB*NN*NC;                     // 192 KB
    float* kw1  = qc + (size_t)NB*NN*NAH;                     // 192 KB
    float* hcf  = kw1 + (size_t)NB*NN*NAH;                    // 192 KB

    embed_kernel<<<NB*NN, 64, 0, stream>>>(coords, ce_w1, ce_b1, ce_w2, ce_b2,
                                           wq, wk, wvw, am_w1, am_b1, pm_w1, pm_w2, pm_b2, am_w2,
                                           maskp, x, vth, qc, kw1, hcf, maskw, w12T, peT, a2P);
    attn_kernel<<<NB*NN/2, 256, 0, stream>>>(pm_b1, out_w, out_b,
                                             x, vth, qc, kw1, hcf,
                                             maskw, w12T, peT, a2P,
                                             (float*)d_out);
}